// Round 9
// baseline (181.218 us; speedup 1.0000x reference)
//
#include <hip/hip_runtime.h>
#include <stdint.h>

#define TOKENS  256
#define INF     4096
#define OUTF    11008
#define NGROUPS 32
#define NTH     256

typedef __attribute__((ext_vector_type(2))) _Float16 f16x2;
typedef __attribute__((ext_vector_type(8))) _Float16 f16x8;
typedef __attribute__((ext_vector_type(2))) __fp16   pkh2;
typedef __attribute__((ext_vector_type(4))) float    f32x4;

union U32H2 { uint32_t u; f16x2 h; };
union H8    { f16x2 h2[4]; f16x8 h8; };
union PK    { pkh2 p; f16x2 h; };

// ---------------- pre-kernel: x fp32 -> fp16, (j, j+4) pair-permuted ---------
__global__ __launch_bounds__(NTH)
void cvt_x(const float* __restrict__ x, _Float16* __restrict__ x16) {
    const int t   = blockIdx.x * NTH + threadIdx.x;   // 0 .. 131071
    const int row = t >> 9;
    const int c   = t & 511;
    const float* p = x + (size_t)row * INF + c * 8;
    f32x4 v0 = *(const f32x4*)p;
    f32x4 v1 = *(const f32x4*)(p + 4);
    H8 o; PK k0, k1, k2, k3;
    k0.p = __builtin_amdgcn_cvt_pkrtz(v0[0], v1[0]);
    k1.p = __builtin_amdgcn_cvt_pkrtz(v0[1], v1[1]);
    k2.p = __builtin_amdgcn_cvt_pkrtz(v0[2], v1[2]);
    k3.p = __builtin_amdgcn_cvt_pkrtz(v0[3], v1[3]);
    o.h2[0] = k0.h; o.h2[1] = k1.h; o.h2[2] = k2.h; o.h2[3] = k3.h;
    *(f16x8*)(x16 + (size_t)row * INF + c * 8) = o.h8;
}

// ---------------- main kernel: 1-wave blocks, zero LDS, zero barriers --------
// R2-R8 evidence: every barrier-coupled design plateaus at 50-60us with all
// pipes <30% busy; the cost tracks the barrier/convoy structure, not prefetch
// depth (R8), phase size (R7), or occupancy (R5/R7). R6 (barrier-free) failed
// only because the compiler never pipelined (VGPR=76 -> zero prefetch).
// R9: explicit register ring-buffers pin the prefetch distances:
//   A-fragments : 4 ksteps deep (~440 cyc) -- covers L2 latency
//   B qweights  : 8 ksteps deep (~880 cyc) -- covers cold-HBM latency
//   scale/zero  : 2 groups  deep (~880 cyc)
// Each of the 1376 waves (grid 344x4) is fully self-paced.
__global__ __launch_bounds__(64, 2)
void qlin_wave(const _Float16* __restrict__ x16,
               const uint32_t* __restrict__ qweight,
               const uint32_t* __restrict__ qzeros,
               const float* __restrict__ scales,
               const float* __restrict__ bias,
               float* __restrict__ out)
{
    const int lane = threadIdx.x;      // 64 threads = 1 wave
    const int bx   = blockIdx.x;       // 0..343  (32-col strip)
    const int by   = blockIdx.y;       // 0..3    (64-row group)

    const int quad = lane >> 4;
    const int l16  = lane & 15;

    // ---- A fragment base: frag(mi, s) = 16B at abase + mi*16*INF + s*32 ----
    const _Float16* abase = x16 + (size_t)(by * 64 + l16) * INF + quad * 8;

    // ---- B columns ----
    const int col0 = bx * 32 + l16;
    const int col1 = col0 + 16;
    const int zsh  = (col0 & 7) * 4;   // same for col1

    f32x4 acc[4][2];
#pragma unroll
    for (int mi = 0; mi < 4; ++mi)
#pragma unroll
        for (int nf = 0; nf < 2; ++nf)
            acc[mi][nf] = f32x4{0.f, 0.f, 0.f, 0.f};

    // ---- register ring buffers ----
    f16x8    af[4][4];        // [s&3][mi]   A-fragments, 4 ksteps deep
    uint32_t Breg[8][2];      // [s&7][nf]   B dwords,    8 ksteps deep
    float    sS[2][2];        // [g&1][nf]   scales,      2 groups deep
    uint32_t qZ[2][2];        // [g&1][nf]   zeros

    // ================= prologue =================
#pragma unroll
    for (int s = 0; s < 4; ++s)
#pragma unroll
        for (int mi = 0; mi < 4; ++mi)
            af[s][mi] = *(const f16x8*)(abase + (size_t)mi * (16 * INF) + s * 32);
#pragma unroll
    for (int s = 0; s < 8; ++s) {
        const uint32_t* qp = qweight + (size_t)(s * 4 + quad) * OUTF;
        Breg[s][0] = qp[col0];
        Breg[s][1] = qp[col1];
    }
#pragma unroll
    for (int g = 0; g < 2; ++g) {
        sS[g][0] = scales[g * OUTF + col0];
        sS[g][1] = scales[g * OUTF + col1];
        qZ[g][0] = qzeros[g * (OUTF / 8) + (col0 >> 3)];
        qZ[g][1] = qzeros[g * (OUTF / 8) + (col1 >> 3)];
    }

    // ================= group loop: 32 groups x 4 ksteps =================
#pragma unroll 1
    for (int g = 0; g < NGROUPS; ++g) {
        // consume this group's constants, then reload the slot for g+2
        f16x2 hs2[2], hz2[2];
#pragma unroll
        for (int nf = 0; nf < 2; ++nf) {
            const float s = sS[g & 1][nf];
            const int   z = (int)((qZ[g & 1][nf] >> zsh) & 15u) + 1025;
            const _Float16 hs = (_Float16)s;
            const _Float16 hz = (_Float16)(-(float)z);
            hs2[nf] = f16x2{hs, hs};
            hz2[nf] = f16x2{hz, hz};
        }
        {
            const int gn = (g + 2 < NGROUPS) ? g + 2 : NGROUPS - 1;
            sS[g & 1][0] = scales[gn * OUTF + col0];
            sS[g & 1][1] = scales[gn * OUTF + col1];
            qZ[g & 1][0] = qzeros[gn * (OUTF / 8) + (col0 >> 3)];
            qZ[g & 1][1] = qzeros[gn * (OUTF / 8) + (col1 >> 3)];
        }

#pragma unroll
        for (int j = 0; j < 4; ++j) {
            const int s = 4 * g + j;          // kstep 0..127

            // ---- dequant this kstep's 2 B dwords ----
            H8 bfr[2];
#pragma unroll
            for (int nf = 0; nf < 2; ++nf) {
                const uint32_t q = Breg[s & 7][nf];
#pragma unroll
                for (int jp = 0; jp < 4; ++jp) {
                    U32H2 u;
                    u.u = ((q >> (4 * jp)) & 0x000F000Fu) | 0x64006400u;
                    bfr[nf].h2[jp] = (u.h + hz2[nf]) * hs2[nf];
                }
            }

            // ---- MFMAs (consume af slot) ----
#pragma unroll
            for (int mi = 0; mi < 4; ++mi) {
#pragma unroll
                for (int nf = 0; nf < 2; ++nf)
                    acc[mi][nf] = __builtin_amdgcn_mfma_f32_16x16x32_f16(
                        af[s & 3][mi], bfr[nf].h8, acc[mi][nf], 0, 0, 0);
            }

            // ---- reload rings: A for s+4, B for s+8 (clamped; idempotent) ----
            const int sA = (s + 4 < 128) ? s + 4 : 127;
            const int sB = (s + 8 < 128) ? s + 8 : 127;
#pragma unroll
            for (int mi = 0; mi < 4; ++mi)
                af[s & 3][mi] = *(const f16x8*)(abase + (size_t)mi * (16 * INF)
                                                + sA * 32);
            {
                const uint32_t* qp = qweight + (size_t)(sB * 4 + quad) * OUTF;
                Breg[s & 7][0] = qp[col0];
                Breg[s & 7][1] = qp[col1];
            }
        }
    }

    // ================= epilogue: direct store + bias =================
#pragma unroll
    for (int nf = 0; nf < 2; ++nf) {
        const int col = (nf == 0) ? col0 : col1;
        const float bv = bias[col];
#pragma unroll
        for (int mi = 0; mi < 4; ++mi) {
            const int r0 = by * 64 + mi * 16 + quad * 4;
#pragma unroll
            for (int rg = 0; rg < 4; ++rg)
                out[(size_t)(r0 + rg) * OUTF + col] = acc[mi][nf][rg] + bv;
        }
    }
}

// ---------------- fallback (proven R2 kernel) if ws too small ----------------
__global__ __launch_bounds__(NTH, 2)
void qlin_fb(const float* __restrict__ x,
             const uint32_t* __restrict__ qweight,
             const uint32_t* __restrict__ qzeros,
             const float* __restrict__ scales,
             const float* __restrict__ bias,
             float* __restrict__ out)
{
    __shared__ alignas(16) _Float16 Asb[64][40];
    __shared__ alignas(16) _Float16 Bsb[128][40];
    const int tid = threadIdx.x;
    const int bx = blockIdx.x, by = blockIdx.y;
    const int am = tid >> 2, ar = tid & 3;
    const float* xrow = x + (size_t)(by * 64 + am) * INF + ar * 8;
    const int bc = tid & 127, br = tid >> 7;
    const int bn = bx * 128 + bc;
    const int bswz = (bc >> 3) & 3;
    const int lane = tid & 63, quad = lane >> 4, l16 = lane & 15;
    const int wv = tid >> 6, wm = wv >> 1, wn = wv & 1;
    f32x4 acc[2][4];
#pragma unroll
    for (int i = 0; i < 2; ++i)
#pragma unroll
        for (int j = 0; j < 4; ++j) acc[i][j] = f32x4{0.f, 0.f, 0.f, 0.f};
    f32x4 pa0 = *(const f32x4*)(xrow + 0);
    f32x4 pa1 = *(const f32x4*)(xrow + 4);
    uint32_t pq0 = qweight[(size_t)br * OUTF + bn];
    uint32_t pq1 = qweight[(size_t)(br + 2) * OUTF + bn];
    for (int g = 0; g < NGROUPS; ++g) {
        const float s = scales[g * OUTF + bn];
        const uint32_t qzv = qzeros[g * (OUTF / 8) + (bn >> 3)];
        const int z = (int)((qzv >> (4 * (bn & 7))) & 15u) + 1;
        const _Float16 hs = (_Float16)s;
        const _Float16 hz = (_Float16)(-(float)(1024 + z));
        const f16x2 hs2 = {hs, hs}, hz2 = {hz, hz};
#pragma unroll
        for (int t4 = 0; t4 < 4; ++t4) {
            const int it = (g << 2) + t4;
            { H8 ah; PK p0, p1, p2, p3;
              p0.p = __builtin_amdgcn_cvt_pkrtz(pa0[0], pa1[0]);
              p1.p = __builtin_amdgcn_cvt_pkrtz(pa0[1], pa1[1]);
              p2.p = __builtin_amdgcn_cvt_pkrtz(pa0[2], pa1[2]);
              p3.p = __builtin_amdgcn_cvt_pkrtz(pa0[3], pa1[3]);
              ah.h2[0] = p0.h; ah.h2[1] = p1.h; ah.h2[2] = p2.h; ah.h2[3] = p3.h;
              *(f16x8*)&Asb[am][ar * 8] = ah.h8; }
            { const uint32_t qq[2] = {pq0, pq1};
#pragma unroll
              for (int rr = 0; rr < 2; ++rr) {
                  const int r = br + rr * 2; H8 bh;
#pragma unroll
                  for (int jp = 0; jp < 4; ++jp) {
                      U32H2 u; u.u = ((qq[rr] >> (4 * jp)) & 0x000F000Fu) | 0x64006400u;
                      bh.h2[jp] = (u.h + hz2) * hs2;
                  }
                  *(f16x8*)&Bsb[bc][(r ^ bswz) * 8] = bh.h8;
              } }
            __syncthreads();
            const int itn = (it < 127) ? it + 1 : 127;
            pa0 = *(const f32x4*)(xrow + itn * 32);
            pa1 = *(const f32x4*)(xrow + itn * 32 + 4);
            pq0 = qweight[(size_t)(itn * 4 + br) * OUTF + bn];
            pq1 = qweight[(size_t)(itn * 4 + br + 2) * OUTF + bn];
            f16x8 af[2], bf[4];
#pragma unroll
            for (int mi = 0; mi < 2; ++mi)
                af[mi] = *(const f16x8*)&Asb[wm * 32 + mi * 16 + l16][quad * 8];
#pragma unroll
            for (int ni = 0; ni < 4; ++ni) {
                const int c = wn * 64 + ni * 16 + l16;
                bf[ni] = *(const f16x8*)&Bsb[c][(quad ^ ((c >> 3) & 3)) * 8];
            }
#pragma unroll
            for (int mi = 0; mi < 2; ++mi)
#pragma unroll
                for (int ni = 0; ni < 4; ++ni)
                    acc[mi][ni] = __builtin_amdgcn_mfma_f32_16x16x32_f16(
                        af[mi], bf[ni], acc[mi][ni], 0, 0, 0);
            __syncthreads();
        }
    }
#pragma unroll
    for (int ni = 0; ni < 4; ++ni) {
        const int col = bx * 128 + wn * 64 + ni * 16 + l16;
        const float bv = bias[col];
#pragma unroll
        for (int mi = 0; mi < 2; ++mi) {
            const int row0 = by * 64 + wm * 32 + mi * 16 + quad * 4;
#pragma unroll
            for (int rg = 0; rg < 4; ++rg)
                out[(size_t)(row0 + rg) * OUTF + col] = acc[mi][ni][rg] + bv;
        }
    }
}

extern "C" void kernel_launch(void* const* d_in, const int* in_sizes, int n_in,
                              void* d_out, int out_size, void* d_ws, size_t ws_size,
                              hipStream_t stream) {
    const float*    xx = (const float*)d_in[0];
    const uint32_t* qw = (const uint32_t*)d_in[1];
    const uint32_t* qz = (const uint32_t*)d_in[2];
    const float*    sc = (const float*)d_in[3];
    const float*    bs = (const float*)d_in[4];
    float* out = (float*)d_out;

    const size_t x16_bytes = (size_t)TOKENS * INF * sizeof(_Float16);  // 2 MB
    if (ws_size >= x16_bytes) {
        _Float16* x16 = (_Float16*)d_ws;
        cvt_x<<<(TOKENS * INF / 8) / NTH, NTH, 0, stream>>>(xx, x16);
        dim3 grid(OUTF / 32, TOKENS / 64);   // 344 x 4 = 1376 one-wave blocks
        qlin_wave<<<grid, 64, 0, stream>>>(x16, qw, qz, sc, bs, out);
    } else {
        dim3 grid(OUTF / 128, TOKENS / 64);
        qlin_fb<<<grid, NTH, 0, stream>>>(xx, qw, qz, sc, bs, out);
    }
}